// Round 4
// baseline (793.778 us; speedup 1.0000x reference)
//
#include <hip/hip_runtime.h>
#include <hip/hip_bf16.h>

// SeqExperts: 64 experts, 128 tokens each, d_model=1024, d_hidden=4096.
// out[e*128+m] = relu(x_e @ W1[e]^T) @ W2[e]^T
// R2: XCD-aware block swizzle (T1).
// R3: counted-vmcnt double-buffer pipeline.
// R4: NO-LDS direct-fragment streaming GEMM. At M=128 each operand row is
//     reused by only 2 waves -> L2 serves the duplication; LDS staging +
//     barriers were pure lockstep overhead. Each wave loads its MFMA
//     fragments straight from global in fragment layout, cvt fp32->bf16
//     in-register for weights, zero barriers in the K-loop. x is
//     pre-converted to bf16 once (tiny pass) so A is always bf16.

typedef __attribute__((ext_vector_type(8))) short bf16x8;   // 8 bf16 (4 VGPRs)
typedef __attribute__((ext_vector_type(4))) float f32x4;    // MFMA C/D frag

#define N_EXPERTS 64
#define DM 1024
#define DH 4096
#define TOKS 128

// RNE fp32 -> bf16
__device__ __forceinline__ unsigned short f2bf(float f) {
    union { float f; unsigned u; } v; v.f = f;
    unsigned r = v.u + 0x7FFFu + ((v.u >> 16) & 1u);
    return (unsigned short)(r >> 16);
}

// elementwise fp32 -> bf16 (8 elems/thread)
__global__ __launch_bounds__(256)
void cvt_bf16(const float* __restrict__ in, unsigned short* __restrict__ outp, int n8) {
    int i = blockIdx.x * blockDim.x + threadIdx.x;
    if (i >= n8) return;
    const float4* p = (const float4*)in + (size_t)i * 2;
    float4 a = p[0], b = p[1];
    ushort4 lo, hi;
    lo.x = f2bf(a.x); lo.y = f2bf(a.y); lo.z = f2bf(a.z); lo.w = f2bf(a.w);
    hi.x = f2bf(b.x); hi.y = f2bf(b.y); hi.z = f2bf(b.z); hi.w = f2bf(b.w);
    ushort4* q = (ushort4*)outp + (size_t)i * 2;
    q[0] = lo; q[1] = hi;
}

// C[128 x N] = A[128 x K] * B[N x K]^T  for expert e. No LDS, no barriers.
// A: bf16, row-major lda=K. B: fp32 weights [N][K]. C: bf16+relu or fp32.
template<int N, int K, bool RELU_OUT_BF16>
__global__ __launch_bounds__(256, 2)
void moe_gemm(const unsigned short* __restrict__ Ab, const float* __restrict__ Bp,
              void* __restrict__ Cp, int nwg_per_xcd)
{
    constexpr int NT = K / 32;      // K-steps of 32 (one MFMA-K per step); NT even
    constexpr int NTILES = N / 128;

    const int tid = threadIdx.x;
    // XCD-aware swizzle (grid % 8 == 0, bijective)
    const int bid = (blockIdx.x & 7) * nwg_per_xcd + (blockIdx.x >> 3);
    const int e   = bid / NTILES;
    const int nt  = bid % NTILES;

    const int lane = tid & 63;
    const int w    = tid >> 6;       // wave 0..3
    const int wr   = w >> 1;         // wave row (0..1)
    const int wc   = w & 1;          // wave col (0..1)
    const int lrow = lane & 15;
    const int kq   = lane >> 4;      // k-quarter (8 elems each)

    // Per-lane fragment base pointers (fragment layout == validated LDS layout:
    // lane (lrow,kq) holds row base+lrow, k = kq*8 .. kq*8+7)
    const unsigned short* aptr =
        Ab + (size_t)(e * TOKS + wr * 64 + lrow) * K + kq * 8;
    const float* bptr =
        Bp + ((size_t)e * N + (size_t)nt * 128 + wc * 64 + lrow) * K + kq * 8;

    f32x4 acc[4][4];
    #pragma unroll
    for (int i = 0; i < 4; ++i)
        #pragma unroll
        for (int n = 0; n < 4; ++n)
            #pragma unroll
            for (int q = 0; q < 4; ++q) acc[i][n][q] = 0.f;

    struct SetA { uint4 v[4]; };                 // 4 A-frags (bf16x8 each)
    struct SetB { float4 lo[4]; float4 hi[4]; }; // 4 B-frags (8 fp32 each)
    SetA a0, a1;
    SetB b0, b1;

    auto LOADA = [&](int t, SetA& s) {
        #pragma unroll
        for (int i = 0; i < 4; ++i)
            s.v[i] = *(const uint4*)(aptr + (size_t)i * 16 * K + t * 32);
    };
    auto LOADB = [&](int t, SetB& s) {
        #pragma unroll
        for (int n = 0; n < 4; ++n) {
            const float* p = bptr + (size_t)n * 16 * K + t * 32;
            s.lo[n] = *(const float4*)p;
            s.hi[n] = *(const float4*)(p + 4);
        }
    };
    auto STEP = [&](const SetA& sa, const SetB& sb) {
        bf16x8 bfr[4];
        #pragma unroll
        for (int n = 0; n < 4; ++n) {
            bf16x8 r;
            r[0] = (short)f2bf(sb.lo[n].x);
            r[1] = (short)f2bf(sb.lo[n].y);
            r[2] = (short)f2bf(sb.lo[n].z);
            r[3] = (short)f2bf(sb.lo[n].w);
            r[4] = (short)f2bf(sb.hi[n].x);
            r[5] = (short)f2bf(sb.hi[n].y);
            r[6] = (short)f2bf(sb.hi[n].z);
            r[7] = (short)f2bf(sb.hi[n].w);
            bfr[n] = r;
        }
        #pragma unroll
        for (int i = 0; i < 4; ++i) {
            bf16x8 af = *(const bf16x8*)&sa.v[i];
            #pragma unroll
            for (int n = 0; n < 4; ++n)
                acc[i][n] = __builtin_amdgcn_mfma_f32_16x16x32_bf16(af, bfr[n], acc[i][n], 0, 0, 0);
        }
    };

    // 1-deep named-set prefetch; no barriers anywhere in the loop.
    LOADA(0, a0); LOADB(0, b0);
    for (int t = 0; t < NT; t += 2) {
        LOADA(t + 1, a1); LOADB(t + 1, b1);   // NT even: t+1 < NT always
        STEP(a0, b0);
        if (t + 2 < NT) { LOADA(t + 2, a0); LOADB(t + 2, b0); }
        STEP(a1, b1);
    }

    // Epilogue. C/D layout (m89-verified): col = lane&15, row = (lane>>4)*4 + reg
    const size_t crow0 = (size_t)e * TOKS;
    if constexpr (RELU_OUT_BF16) {
        unsigned short* C = (unsigned short*)Cp;
        #pragma unroll
        for (int i = 0; i < 4; ++i)
            #pragma unroll
            for (int n = 0; n < 4; ++n)
                #pragma unroll
                for (int q = 0; q < 4; ++q) {
                    const int row = wr * 64 + i * 16 + kq * 4 + q;
                    const int col = nt * 128 + wc * 64 + n * 16 + lrow;
                    C[(crow0 + row) * N + col] = f2bf(fmaxf(acc[i][n][q], 0.f));
                }
    } else {
        float* C = (float*)Cp;
        #pragma unroll
        for (int i = 0; i < 4; ++i)
            #pragma unroll
            for (int n = 0; n < 4; ++n)
                #pragma unroll
                for (int q = 0; q < 4; ++q) {
                    const int row = wr * 64 + i * 16 + kq * 4 + q;
                    const int col = nt * 128 + wc * 64 + n * 16 + lrow;
                    C[(crow0 + row) * N + col] = acc[i][n][q];
                }
    }
}

extern "C" void kernel_launch(void* const* d_in, const int* in_sizes, int n_in,
                              void* d_out, int out_size, void* d_ws, size_t ws_size,
                              hipStream_t stream) {
    const float* inputs = (const float*)d_in[0];   // [8192, 1024] fp32
    const float* w1     = (const float*)d_in[1];   // [64, 4096, 1024] fp32
    const float* w2     = (const float*)d_in[2];   // [64, 1024, 4096] fp32
    // d_in[3] = splits (always 128) -- unused

    unsigned short* h  = (unsigned short*)d_ws;                          // 64 MiB bf16
    unsigned short* xb = (unsigned short*)((char*)d_ws + (size_t)64 * 1024 * 1024); // 16 MiB bf16
    float* out = (float*)d_out;                    // [8192, 1024] fp32

    // Pre-pass: x fp32 -> bf16 (8192*1024 elems, 8 per thread)
    const int n8 = (TOKS * N_EXPERTS) * DM / 8;    // 1,048,576
    cvt_bf16<<<dim3(n8 / 256), dim3(256), 0, stream>>>(inputs, xb, n8);

    // Pass 1: h = relu(x @ w1^T), bf16. grid = 64*32 = 2048
    moe_gemm<DH, DM, true><<<dim3(N_EXPERTS * (DH / 128)), dim3(256), 0, stream>>>(
        xb, w1, h, N_EXPERTS * (DH / 128) / 8);
    // Pass 2: out = h @ w2^T, fp32. grid = 64*8 = 512
    moe_gemm<DM, DH, false><<<dim3(N_EXPERTS * (DM / 128)), dim3(256), 0, stream>>>(
        h, w2, out, N_EXPERTS * (DM / 128) / 8);
}

// Round 5
// 707.213 us; speedup vs baseline: 1.1224x; 1.1224x over previous
//
#include <hip/hip_runtime.h>
#include <hip/hip_bf16.h>

// SeqExperts: 64 experts, 128 tokens each, d_model=1024, d_hidden=4096.
// out[e*128+m] = relu(x_e @ W1[e]^T) @ W2[e]^T
// R2: XCD-aware block swizzle (T1).
// R3: counted-vmcnt double-buffer pipeline (best so far, 540us).
// R4: no-LDS direct-fragment (FAILED 794us: B dup x2 conv in critical path).
// R5: R3 structure + BK=64 (half the barriers, 2x in-flight per set)
//     + 16B-chunk XOR swizzle on LDS tiles (kills 8-way ds_read_b128 conflict)
//     + x pre-converted to bf16 (A staging = pure copy in both passes).

typedef __attribute__((ext_vector_type(8))) short bf16x8;   // 8 bf16 (4 VGPRs)
typedef __attribute__((ext_vector_type(4))) float f32x4;    // MFMA C/D frag

#define N_EXPERTS 64
#define DM 1024
#define DH 4096
#define TOKS 128

// RNE fp32 -> bf16
__device__ __forceinline__ unsigned short f2bf(float f) {
    union { float f; unsigned u; } v; v.f = f;
    unsigned r = v.u + 0x7FFFu + ((v.u >> 16) & 1u);
    return (unsigned short)(r >> 16);
}

// elementwise fp32 -> bf16 (8 elems/thread)
__global__ __launch_bounds__(256)
void cvt_bf16(const float* __restrict__ in, unsigned short* __restrict__ outp, int n8) {
    int i = blockIdx.x * blockDim.x + threadIdx.x;
    if (i >= n8) return;
    const float4* p = (const float4*)in + (size_t)i * 2;
    float4 a = p[0], b = p[1];
    ushort4 lo, hi;
    lo.x = f2bf(a.x); lo.y = f2bf(a.y); lo.z = f2bf(a.z); lo.w = f2bf(a.w);
    hi.x = f2bf(b.x); hi.y = f2bf(b.y); hi.z = f2bf(b.z); hi.w = f2bf(b.w);
    ushort4* q = (ushort4*)outp + (size_t)i * 2;
    q[0] = lo; q[1] = hi;
}

// C[128 x N] = A[128 x K] * B[N x K]^T for expert e.
// A: bf16 row-major lda=K. B: fp32 weights [N][K]. C: bf16+relu or fp32.
// LDS tiles: [128 rows][8 chunks of 16B], chunk swizzle c ^= (row>>1)&7.
template<int N, int K, bool RELU_OUT_BF16>
__global__ __launch_bounds__(256, 2)
void moe_gemm(const unsigned short* __restrict__ Ab, const float* __restrict__ Bp,
              void* __restrict__ Cp, int nwg_per_xcd)
{
    constexpr int BK = 64;          // K elems per tile (128 B rows, 8 chunks)
    constexpr int NT = K / BK;      // 16 (pass1) / 64 (pass2); even
    constexpr int NTILES = N / 128;

    __shared__ unsigned short sA[2][128][BK];  // 16 KiB per buf
    __shared__ unsigned short sB[2][128][BK];

    const int tid = threadIdx.x;
    const int bid = (blockIdx.x & 7) * nwg_per_xcd + (blockIdx.x >> 3);
    const int e   = bid / NTILES;
    const int nt  = bid % NTILES;

    const int lane = tid & 63;
    const int w    = tid >> 6;       // wave 0..3
    const int wr   = w >> 1;
    const int wc   = w & 1;
    const int lrow = lane & 15;
    const int kq   = lane >> 4;      // 0..3

    // ---- staging decomposition: row = tid>>1 (0..127), half h = tid&1 (chunks 4h..4h+3)
    const int srow = tid >> 1;
    const int shalf = tid & 1;
    const int sswz = (srow >> 1) & 7;                 // row's chunk XOR

    const unsigned short* aRow = Ab + (size_t)(e * TOKS + srow) * K;
    const float*          bRow = Bp + ((size_t)e * N + (size_t)nt * 128 + srow) * K;

    // ---- fragment-read chunk offsets (per-lane constants; see derivation in theory)
    const int sl = (lrow >> 1) & 7;
    const int offk0 = ((0 * 4 + kq) ^ sl) * 8;        // elem offset in row, k-half 0
    const int offk1 = ((1 * 4 + kq) ^ sl) * 8;        // k-half 1

    f32x4 acc[4][4];
    #pragma unroll
    for (int i = 0; i < 4; ++i)
        #pragma unroll
        for (int n = 0; n < 4; ++n)
            #pragma unroll
            for (int q = 0; q < 4; ++q) acc[i][n][q] = 0.f;

    struct Regs {
        uint4  a[4];    // 4 x 16B bf16 chunks (64 B contiguous)
        float4 b[8];    // 4 chunks x 2 float4 (128 B contiguous fp32)
    };
    Regs r0, r1;

    auto LOAD = [&](int t, Regs& r) {
        const unsigned short* ap = aRow + t * BK + shalf * 32;  // 64 B
        #pragma unroll
        for (int i = 0; i < 4; ++i)
            r.a[i] = *(const uint4*)(ap + i * 8);
        const float* bp = bRow + t * BK + shalf * 32;           // 256 B
        #pragma unroll
        for (int i = 0; i < 8; ++i)
            r.b[i] = *(const float4*)(bp + i * 4);
    };

    auto WRITE = [&](int buf, Regs& r) {
        #pragma unroll
        for (int i = 0; i < 4; ++i) {
            const int c = (shalf * 4 + i) ^ sswz;
            *(uint4*)&sA[buf][srow][c * 8] = r.a[i];
        }
        #pragma unroll
        for (int i = 0; i < 4; ++i) {
            const int c = (shalf * 4 + i) ^ sswz;
            uint4 u;
            float4 lo = r.b[i * 2], hi = r.b[i * 2 + 1];
            u.x = (unsigned)f2bf(lo.x) | ((unsigned)f2bf(lo.y) << 16);
            u.y = (unsigned)f2bf(lo.z) | ((unsigned)f2bf(lo.w) << 16);
            u.z = (unsigned)f2bf(hi.x) | ((unsigned)f2bf(hi.y) << 16);
            u.w = (unsigned)f2bf(hi.z) | ((unsigned)f2bf(hi.w) << 16);
            *(uint4*)&sB[buf][srow][c * 8] = u;
        }
    };

    auto COMPUTE = [&](int buf) {
        #pragma unroll
        for (int kh = 0; kh < 2; ++kh) {
            const int off = kh ? offk1 : offk0;
            bf16x8 af[4], bfr[4];
            #pragma unroll
            for (int i = 0; i < 4; ++i)
                af[i] = *(const bf16x8*)&sA[buf][wr * 64 + i * 16 + lrow][off];
            #pragma unroll
            for (int n = 0; n < 4; ++n)
                bfr[n] = *(const bf16x8*)&sB[buf][wc * 64 + n * 16 + lrow][off];
            #pragma unroll
            for (int i = 0; i < 4; ++i)
                #pragma unroll
                for (int n = 0; n < 4; ++n)
                    acc[i][n] = __builtin_amdgcn_mfma_f32_16x16x32_bf16(af[i], bfr[n], acc[i][n], 0, 0, 0);
        }
    };

    // Prologue: 2 tiles in flight.
    LOAD(0, r0);
    LOAD(1, r1);
    WRITE(0, r0);                          // waits only r0's loads (counted vmcnt)
    asm volatile("s_waitcnt lgkmcnt(0)" ::: "memory");
    __builtin_amdgcn_s_barrier();

    for (int t = 0; t < NT; t += 2) {
        if (t + 2 < NT) LOAD(t + 2, r0);
        COMPUTE(0);
        if (t + 1 < NT) WRITE(1, r1);      // r0's 12 newer loads stay in flight
        asm volatile("s_waitcnt lgkmcnt(0)" ::: "memory");
        __builtin_amdgcn_s_barrier();

        if (t + 3 < NT) LOAD(t + 3, r1);
        COMPUTE(1);
        if (t + 2 < NT) WRITE(0, r0);
        asm volatile("s_waitcnt lgkmcnt(0)" ::: "memory");
        __builtin_amdgcn_s_barrier();
    }

    // Epilogue. C/D layout (m89-verified): col = lane&15, row = (lane>>4)*4 + reg
    const size_t crow0 = (size_t)e * TOKS;
    if constexpr (RELU_OUT_BF16) {
        unsigned short* C = (unsigned short*)Cp;
        #pragma unroll
        for (int i = 0; i < 4; ++i)
            #pragma unroll
            for (int n = 0; n < 4; ++n)
                #pragma unroll
                for (int q = 0; q < 4; ++q) {
                    const int row = wr * 64 + i * 16 + kq * 4 + q;
                    const int col = nt * 128 + wc * 64 + n * 16 + lrow;
                    C[(crow0 + row) * N + col] = f2bf(fmaxf(acc[i][n][q], 0.f));
                }
    } else {
        float* C = (float*)Cp;
        #pragma unroll
        for (int i = 0; i < 4; ++i)
            #pragma unroll
            for (int n = 0; n < 4; ++n)
                #pragma unroll
                for (int q = 0; q < 4; ++q) {
                    const int row = wr * 64 + i * 16 + kq * 4 + q;
                    const int col = nt * 128 + wc * 64 + n * 16 + lrow;
                    C[(crow0 + row) * N + col] = acc[i][n][q];
                }
    }
}

extern "C" void kernel_launch(void* const* d_in, const int* in_sizes, int n_in,
                              void* d_out, int out_size, void* d_ws, size_t ws_size,
                              hipStream_t stream) {
    const float* inputs = (const float*)d_in[0];   // [8192, 1024] fp32
    const float* w1     = (const float*)d_in[1];   // [64, 4096, 1024] fp32
    const float* w2     = (const float*)d_in[2];   // [64, 1024, 4096] fp32
    // d_in[3] = splits (always 128) -- unused

    unsigned short* h  = (unsigned short*)d_ws;                                     // 64 MiB
    unsigned short* xb = (unsigned short*)((char*)d_ws + (size_t)64 * 1024 * 1024); // 16 MiB
    float* out = (float*)d_out;

    // Pre-pass: x fp32 -> bf16
    const int n8 = (TOKS * N_EXPERTS) * DM / 8;    // 1,048,576
    cvt_bf16<<<dim3(n8 / 256), dim3(256), 0, stream>>>(inputs, xb, n8);

    // Pass 1: h = relu(x @ w1^T), bf16. grid = 64*32 = 2048
    moe_gemm<DH, DM, true><<<dim3(N_EXPERTS * (DH / 128)), dim3(256), 0, stream>>>(
        xb, w1, h, N_EXPERTS * (DH / 128) / 8);
    // Pass 2: out = h @ w2^T, fp32. grid = 64*8 = 512
    moe_gemm<DM, DH, false><<<dim3(N_EXPERTS * (DM / 128)), dim3(256), 0, stream>>>(
        h, w2, out, N_EXPERTS * (DM / 128) / 8);
}

// Round 6
// 521.129 us; speedup vs baseline: 1.5232x; 1.3571x over previous
//
#include <hip/hip_runtime.h>
#include <hip/hip_bf16.h>

// SeqExperts: 64 experts, 128 tokens each, d_model=1024, d_hidden=4096.
// out[e*128+m] = relu(x_e @ W1[e]^T) @ W2[e]^T
// R3 (best=540us): counted-vmcnt double-buffer pipeline, XCD swizzle, BK=32.
// R4 (794us FAIL): no-LDS direct-fragment (B dup + cvt on critical path).
// R5 (707us FAIL): BK=64 bundle, but staging decomposition broke coalescing
//     (16B per lane scattered across 32+ cache lines per instruction).
// R6: R3 skeleton, coalesced staging kept, + BK=64 (half the barriers,
//     2x in-flight/set) + chunk-XOR LDS swizzle (both sides, reg-staged)
//     + cheap round-half-up bf16 pack (3 ops/2 elems vs ~8)
//     + nontemporal weight loads (protect L2 slabs) + x->bf16 prepass.

typedef __attribute__((ext_vector_type(8))) short bf16x8;   // 8 bf16 (4 VGPRs)
typedef __attribute__((ext_vector_type(4))) float f32x4;
typedef __attribute__((ext_vector_type(4))) unsigned int u32x4;

#define N_EXPERTS 64
#define DM 1024
#define DH 4096
#define TOKS 128

__device__ __forceinline__ unsigned f2u(float f) {
    union { float f; unsigned u; } v; v.f = f; return v.u;
}
// round-half-up fp32->bf16 (0.5 ulp, same bound as RNE; no NaN/inf in data)
__device__ __forceinline__ unsigned short f2bf(float f) {
    return (unsigned short)((f2u(f) + 0x8000u) >> 16);
}
// pack two fp32 -> 2xbf16 in one u32 (lo in bits 0-15, hi in bits 16-31)
__device__ __forceinline__ unsigned pack2(float lo, float hi) {
    return ((f2u(lo) + 0x8000u) >> 16) | ((f2u(hi) + 0x8000u) & 0xFFFF0000u);
}

// elementwise fp32 -> bf16 (8 elems/thread)
__global__ __launch_bounds__(256)
void cvt_bf16(const float* __restrict__ in, unsigned* __restrict__ outp, int n8) {
    int i = blockIdx.x * blockDim.x + threadIdx.x;
    if (i >= n8) return;
    const f32x4* p = (const f32x4*)in + (size_t)i * 2;
    f32x4 a = p[0], b = p[1];
    u32x4 o = { pack2(a[0], a[1]), pack2(a[2], a[3]),
                pack2(b[0], b[1]), pack2(b[2], b[3]) };
    *((u32x4*)outp + i) = o;
}

// C[128 x N] = A[128 x K] * B[N x K]^T for expert e.
// A: bf16 row-major lda=K. B: fp32 weights [N][K]. C: bf16+relu or fp32.
// LDS tiles [128][64] bf16, 16B chunks XOR-swizzled: chunk c stored at c^((row>>1)&7).
template<int N, int K, bool RELU_OUT_BF16>
__global__ __launch_bounds__(256, 2)
void moe_gemm(const unsigned short* __restrict__ Ab, const float* __restrict__ Bp,
              void* __restrict__ Cp, int nwg_per_xcd)
{
    constexpr int BK = 64;          // K elems per tile (128 B bf16 rows, 8 chunks)
    constexpr int NT = K / BK;      // 16 (pass1) / 64 (pass2); even
    constexpr int NTILES = N / 128;

    __shared__ unsigned short sA[2][128][BK];  // 16 KiB per buf
    __shared__ unsigned short sB[2][128][BK];

    const int tid = threadIdx.x;
    const int bid = (blockIdx.x & 7) * nwg_per_xcd + (blockIdx.x >> 3);
    const int e   = bid / NTILES;
    const int nt  = bid % NTILES;

    const int lane = tid & 63;
    const int w    = tid >> 6;       // wave 0..3
    const int wr   = w >> 1;
    const int wc   = w & 1;
    const int lrow = lane & 15;
    const int kq   = lane >> 4;      // 0..3

    // ---- staging: 8 lanes cover one row's full BK range contiguously.
    //      rows arow + j*32 (j=0..3). COALESCED: per instruction, lanes 0-7
    //      read 128B (A, bf16) / 256B (B, fp32) contiguous.
    const int arow = tid >> 3;       // 0..31
    const int ac   = tid & 7;        // chunk id 0..7
    const int swz  = (arow >> 1) & 7;  // (j*32>>1) % 8 == 0, so j-independent

    const unsigned short* aBase = Ab + (size_t)(e * TOKS + arow) * K + ac * 8;
    const float*          bBase = Bp + ((size_t)e * N + (size_t)nt * 128 + arow) * K + ac * 8;

    // ---- fragment-read chunk offsets (per-lane constants).
    //      frag row r = *64 + i*16 + lrow -> (r>>1)&7 == (lrow>>1)&7 for all i.
    const int sl = (lrow >> 1) & 7;
    const int offk0 = ((kq + 0) ^ sl) * 8;   // k-half 0 (k = kq*8)
    const int offk1 = ((kq + 4) ^ sl) * 8;   // k-half 1 (k = 32 + kq*8)

    f32x4 acc[4][4];
    #pragma unroll
    for (int i = 0; i < 4; ++i)
        #pragma unroll
        for (int n = 0; n < 4; ++n)
            #pragma unroll
            for (int q = 0; q < 4; ++q) acc[i][n][q] = 0.f;

    struct Regs {
        u32x4 a[4];    // 4 x 16B bf16 chunks (rows j*32)
        f32x4 b[8];    // 4 rows x 2 float4 (32B contiguous per row)
    };
    Regs r0, r1;

    auto LOAD = [&](int t, Regs& r) {
        #pragma unroll
        for (int j = 0; j < 4; ++j)
            r.a[j] = *(const u32x4*)(aBase + (size_t)j * 32 * K + t * BK);
        #pragma unroll
        for (int j = 0; j < 4; ++j) {
            const f32x4* p = (const f32x4*)(bBase + (size_t)j * 32 * K + t * BK);
            r.b[2 * j]     = __builtin_nontemporal_load(p);      // weights: read-once,
            r.b[2 * j + 1] = __builtin_nontemporal_load(p + 1);  // don't pollute L2
        }
    };

    auto WRITE = [&](int buf, Regs& r) {
        const int c8 = (ac ^ swz) * 8;
        #pragma unroll
        for (int j = 0; j < 4; ++j)
            *(u32x4*)&sA[buf][arow + j * 32][c8] = r.a[j];
        #pragma unroll
        for (int j = 0; j < 4; ++j) {
            f32x4 lo = r.b[2 * j], hi = r.b[2 * j + 1];
            u32x4 u = { pack2(lo[0], lo[1]), pack2(lo[2], lo[3]),
                        pack2(hi[0], hi[1]), pack2(hi[2], hi[3]) };
            *(u32x4*)&sB[buf][arow + j * 32][c8] = u;
        }
    };

    auto COMPUTE = [&](int buf) {
        #pragma unroll
        for (int kh = 0; kh < 2; ++kh) {
            const int off = kh ? offk1 : offk0;
            bf16x8 af[4], bfr[4];
            #pragma unroll
            for (int i = 0; i < 4; ++i)
                af[i] = *(const bf16x8*)&sA[buf][wr * 64 + i * 16 + lrow][off];
            #pragma unroll
            for (int n = 0; n < 4; ++n)
                bfr[n] = *(const bf16x8*)&sB[buf][wc * 64 + n * 16 + lrow][off];
            #pragma unroll
            for (int i = 0; i < 4; ++i)
                #pragma unroll
                for (int n = 0; n < 4; ++n)
                    acc[i][n] = __builtin_amdgcn_mfma_f32_16x16x32_bf16(af[i], bfr[n], acc[i][n], 0, 0, 0);
        }
    };

    // Prologue: 2 tiles in flight.
    LOAD(0, r0);
    LOAD(1, r1);
    WRITE(0, r0);                          // waits only r0's loads (counted vmcnt)
    asm volatile("s_waitcnt lgkmcnt(0)" ::: "memory");
    __builtin_amdgcn_s_barrier();

    for (int t = 0; t < NT; t += 2) {
        if (t + 2 < NT) LOAD(t + 2, r0);
        COMPUTE(0);
        if (t + 1 < NT) WRITE(1, r1);      // r0's 12 newer loads stay in flight
        asm volatile("s_waitcnt lgkmcnt(0)" ::: "memory");
        __builtin_amdgcn_s_barrier();

        if (t + 3 < NT) LOAD(t + 3, r1);
        COMPUTE(1);
        if (t + 2 < NT) WRITE(0, r0);
        asm volatile("s_waitcnt lgkmcnt(0)" ::: "memory");
        __builtin_amdgcn_s_barrier();
    }

    // Epilogue. C/D layout (m89-verified): col = lane&15, row = (lane>>4)*4 + reg
    const size_t crow0 = (size_t)e * TOKS;
    if constexpr (RELU_OUT_BF16) {
        unsigned short* C = (unsigned short*)Cp;
        #pragma unroll
        for (int i = 0; i < 4; ++i)
            #pragma unroll
            for (int n = 0; n < 4; ++n)
                #pragma unroll
                for (int q = 0; q < 4; ++q) {
                    const int row = wr * 64 + i * 16 + kq * 4 + q;
                    const int col = nt * 128 + wc * 64 + n * 16 + lrow;
                    C[(crow0 + row) * N + col] = f2bf(fmaxf(acc[i][n][q], 0.f));
                }
    } else {
        float* C = (float*)Cp;
        #pragma unroll
        for (int i = 0; i < 4; ++i)
            #pragma unroll
            for (int n = 0; n < 4; ++n)
                #pragma unroll
                for (int q = 0; q < 4; ++q) {
                    const int row = wr * 64 + i * 16 + kq * 4 + q;
                    const int col = nt * 128 + wc * 64 + n * 16 + lrow;
                    C[(crow0 + row) * N + col] = acc[i][n][q];
                }
    }
}

extern "C" void kernel_launch(void* const* d_in, const int* in_sizes, int n_in,
                              void* d_out, int out_size, void* d_ws, size_t ws_size,
                              hipStream_t stream) {
    const float* inputs = (const float*)d_in[0];   // [8192, 1024] fp32
    const float* w1     = (const float*)d_in[1];   // [64, 4096, 1024] fp32
    const float* w2     = (const float*)d_in[2];   // [64, 1024, 4096] fp32
    // d_in[3] = splits (always 128) -- unused

    unsigned short* h  = (unsigned short*)d_ws;                                     // 64 MiB
    unsigned short* xb = (unsigned short*)((char*)d_ws + (size_t)64 * 1024 * 1024); // 16 MiB
    float* out = (float*)d_out;

    // Pre-pass: x fp32 -> bf16
    const int n8 = (TOKS * N_EXPERTS) * DM / 8;    // 1,048,576
    cvt_bf16<<<dim3(n8 / 256), dim3(256), 0, stream>>>(inputs, (unsigned*)xb, n8);

    // Pass 1: h = relu(x @ w1^T), bf16. grid = 64*32 = 2048
    moe_gemm<DH, DM, true><<<dim3(N_EXPERTS * (DH / 128)), dim3(256), 0, stream>>>(
        xb, w1, h, N_EXPERTS * (DH / 128) / 8);
    // Pass 2: out = h @ w2^T, fp32. grid = 64*8 = 512
    moe_gemm<DM, DH, false><<<dim3(N_EXPERTS * (DM / 128)), dim3(256), 0, stream>>>(
        h, w2, out, N_EXPERTS * (DM / 128) / 8);
}